// Round 8
// baseline (714.316 us; speedup 1.0000x reference)
//
#include <hip/hip_runtime.h>
#include <cstdint>

typedef __attribute__((ext_vector_type(8))) _Float16 f16x8;
typedef __attribute__((ext_vector_type(4))) float f32x4;
typedef __attribute__((ext_vector_type(4))) int i32x4;

#define SEQL 256

// ws byte offsets
#define WS_B0H   0        // hi f16 B0: [3 ks][16 nt][64 lane][8] = 49152 B
#define WS_B1H   49152    // hi f16 B1: [4][16][64][8] = 65536 B
#define WS_LO8   114688   // fp8-e4m3 lo (x2048): B0 24576 B then B1 32768 B
#define WS_BIAS  172032   // 512 f32: L1 cells*4+gate (256), then L2 (256)

// LDS layout (per 4-wave block; x2 blocks/CU = 148.7 KB of 160)
#define L_LO8   0         // fp8 lo weights, copied verbatim from ws (57344)
#define L_FEX   57344     // f16 h-exchange: 16 rows x 528 B
#define FEXSTR  528
#define L_8EX   65792     // fp8 h-exchange: 16 rows x 272 B
#define EX8STR  272
#define L_BIAS  70144     // 512 f32
#define L_HD    72192     // head exchange: 8 rows x 272 B
#define HDSTR   272
#define LDS_TOTAL 74368

#define NEG_L   -1.4426950408889634f   // -log2(e)
#define NEG_2L  -2.8853900817779268f   // -2*log2(e)
#define LO_SCALE 2048.0f
#define LO_INV   4.8828125e-4f         // 1/2048

__device__ __forceinline__ float ex2(float x) { return __builtin_amdgcn_exp2f(x); }
__device__ __forceinline__ float rcp_(float x) { return __builtin_amdgcn_rcpf(x); }
__device__ __forceinline__ f32x4 mfma16(f16x8 a, f16x8 b, f32x4 c) {
  return __builtin_amdgcn_mfma_f32_16x16x32_f16(a, b, c, 0, 0, 0);
}
__device__ __forceinline__ f32x4 mfma8(long a, long b, f32x4 c) {
  return __builtin_amdgcn_mfma_f32_16x16x32_fp8_fp8(a, b, c, 0, 0, 0);
}
__device__ __forceinline__ f16x8 zero8() {
  f16x8 z;
#pragma unroll
  for (int i = 0; i < 8; ++i) z[i] = (_Float16)0.f;
  return z;
}
__device__ __forceinline__ f16x8 cvt8(f32x4 a, f32x4 b) {
  f16x8 r;
#pragma unroll
  for (int j = 0; j < 4; ++j) r[j] = (_Float16)a[j];
#pragma unroll
  for (int j = 0; j < 4; ++j) r[4 + j] = (_Float16)b[j];
  return r;
}
// pack 8 f32 -> 8 fp8-e4m3 bytes in K order (byte0 = a[0])
__device__ __forceinline__ long packfp8(f32x4 a, f32x4 b) {
  int lo = __builtin_amdgcn_cvt_pk_fp8_f32(a[0], a[1], 0, false);
  lo = __builtin_amdgcn_cvt_pk_fp8_f32(a[2], a[3], lo, true);
  int hi = __builtin_amdgcn_cvt_pk_fp8_f32(b[0], b[1], 0, false);
  hi = __builtin_amdgcn_cvt_pk_fp8_f32(b[2], b[3], hi, true);
  return ((long)(unsigned)hi << 32) | (unsigned)lo;
}
__device__ __forceinline__ unsigned char fp8byte(float v) {
  return (unsigned char)(__builtin_amdgcn_cvt_pk_fp8_f32(v, v, 0, false) & 0xff);
}

// Pack weights: hi f16 (MFMA A-frag order, as all prior rounds) + lo as
// fp8-e4m3 of residual*2048 (same frag order, 1 byte/elem). Pre-scaled by
// -log2e (i,f,o) / -2log2e (g).
__global__ __launch_bounds__(256) void prep(
    const float* __restrict__ Wih0, const float* __restrict__ Whh0,
    const float* __restrict__ bih0, const float* __restrict__ bhh0,
    const float* __restrict__ Wih1, const float* __restrict__ Whh1,
    const float* __restrict__ bih1, const float* __restrict__ bhh1,
    unsigned char* __restrict__ ws) {
  int e = blockIdx.x * 256 + threadIdx.x;
  if (e < 24576) {  // B0: K=96 = [x(32)|h1(64)]
    int j = e & 7, lane = (e >> 3) & 63, nt = (e >> 9) & 15, ks = e >> 13;
    int kdim = ks * 32 + (lane >> 4) * 8 + j;
    int col = nt * 16 + (lane & 15);
    int ko = col >> 2, g = col & 3;
    float w = (kdim < 32) ? Wih0[(g * 64 + ko) * 32 + kdim]
                          : Whh0[(g * 64 + ko) * 64 + (kdim - 32)];
    w *= (g == 2) ? NEG_2L : NEG_L;
    _Float16 hi = (_Float16)w;
    float lo = (w - (float)hi) * LO_SCALE;
    ((_Float16*)(ws + WS_B0H))[e] = hi;
    (ws + WS_LO8)[e] = fp8byte(lo);
  } else if (e < 57344) {  // B1: K=128 = [h1(64)|h2(64)]
    int r = e - 24576;
    int j = r & 7, lane = (r >> 3) & 63, nt = (r >> 9) & 15, ks = r >> 13;
    int kdim = ks * 32 + (lane >> 4) * 8 + j;
    int col = nt * 16 + (lane & 15);
    int ko = col >> 2, g = col & 3;
    float w = (kdim < 64) ? Wih1[(g * 64 + ko) * 64 + kdim]
                          : Whh1[(g * 64 + ko) * 64 + (kdim - 64)];
    w *= (g == 2) ? NEG_2L : NEG_L;
    _Float16 hi = (_Float16)w;
    float lo = (w - (float)hi) * LO_SCALE;
    ((_Float16*)(ws + WS_B1H))[r] = hi;
    (ws + WS_LO8 + 24576)[r] = fp8byte(lo);
  } else if (e < 57856) {  // biases (pre-scaled, fp32): L1 then L2
    int r = e - 57344;
    int col = r & 255, ko = col >> 2, g = col & 3;
    float v = (r < 256) ? bih0[g * 64 + ko] + bhh0[g * 64 + ko]
                        : bih1[g * 64 + ko] + bhh1[g * 64 + ko];
    v *= (g == 2) ? NEG_2L : NEG_L;
    ((float*)(ws + WS_BIAS))[r] = v;
  }
}

// v13: de-phase via TWO barrier domains per CU. 4-wave blocks x 8 batch x
// 512 blocks -> 2 blocks/CU, 1 wave of each block per SIMD; block B's MFMAs
// fill block A's barrier/chain stalls (hardware wave arbitration).
// Register fit: hi f16 weights in regs (112/wave: 4 ntiles x 7 K-chunks);
// lo residuals as fp8-e4m3 in LDS (57 KB/block), consumed by fp8 MFMAs with
// fp8 side-copies of activations. N=8 of 16 tile cols used (cost: 2x MFMA
// instr, the new floor ~2172 cyc/SIMD/interval).
__global__ __launch_bounds__(256, 2) void lstm_mfma13(
    const float* __restrict__ x, const unsigned char* __restrict__ ws,
    const float* __restrict__ W1, const float* __restrict__ b1,
    const float* __restrict__ W2, const float* __restrict__ b2,
    float* __restrict__ out) {
  __shared__ __align__(16) unsigned char lds[LDS_TOTAL];
  const int tid = threadIdx.x;
  const int lane = tid & 63, wave = tid >> 6;  // 4 waves, ntiles wave+4m
  const int q = lane >> 4, mcol = lane & 15;
  const bool act = mcol < 8;

  // ---- init: copy lo8 + biases to LDS, zero both exchanges ----
  for (int i = tid; i < 3584; i += 256)
    ((i32x4*)(lds + L_LO8))[i] = ((const i32x4*)(ws + WS_LO8))[i];
  for (int i = tid; i < 512; i += 256)
    ((float*)(lds + L_BIAS))[i] = ((const float*)(ws + WS_BIAS))[i];
  for (int i = tid; i < 3200; i += 256)
    ((unsigned*)(lds + L_FEX))[i] = 0u;  // f16 + fp8 exch (contiguous)

  // ---- hi weight fragments -> registers (112 VGPR) ----
  f16x8 w0h[4][3], w1h[4][4];
#pragma unroll
  for (int m = 0; m < 4; ++m) {
    const int nt = wave + 4 * m;
#pragma unroll
    for (int ks = 0; ks < 3; ++ks)
      w0h[m][ks] = ((const f16x8*)(ws + WS_B0H))[(ks * 16 + nt) * 64 + lane];
#pragma unroll
    for (int ks = 0; ks < 4; ++ks)
      w1h[m][ks] = ((const f16x8*)(ws + WS_B1H))[(ks * 16 + nt) * 64 + lane];
  }
  f32x4 z4;
  z4[0] = z4[1] = z4[2] = z4[3] = 0.f;

  // x: lane owns batch blockIdx*8 + (mcol&7), dims 8q..8q+7 (32 B)
  const float* xp =
      x + (size_t)(blockIdx.x * 8 + (mcol & 7)) * (SEQL * 32) + q * 8;
  f32x4 xa = *(const f32x4*)(xp);
  f32x4 xb = *(const f32x4*)(xp + 4);

  __syncthreads();

  f16x8 ax = cvt8(xa, xb);   // x(0)
  long ax8 = packfp8(xa, xb);
  f16x8 ah1f[2], ah2f[2];
  ah1f[0] = ah1f[1] = ah2f[0] = ah2f[1] = zero8();
  long fh1[2] = {0, 0}, fh2[2] = {0, 0};
  float c1[4] = {0.f, 0.f, 0.f, 0.f}, c2[4] = {0.f, 0.f, 0.f, 0.f};

  const int rdF = mcol * FEXSTR + q * 16;  // f16 frag read base (+slot+ks*64)
  const int rd8 = mcol * EX8STR + q * 8;   // fp8 frag read base (+slot+ks*32)

  // static fp8-lo weight fragments (never rewritten -> no barrier hazard)
  auto lo0 = [&](int ks, int m) -> long {
    return *(const long*)(lds + L_LO8 + ((ks * 16 + wave + 4 * m) * 64 + lane) * 8);
  };
  auto lo1 = [&](int ks, int m) -> long {
    return *(const long*)(lds + L_LO8 + 24576 +
                          ((ks * 16 + wave + 4 * m) * 64 + lane) * 8);
  };

  // fused cell: 8 trans. p = bias + accH + accL/2048 (pre-scaled domain).
  auto cellfn = [&](const f32x4& aH, const f32x4& aL, const f32x4& bv,
                    float& c) -> float {
    float p0 = fmaf(aL[0], LO_INV, aH[0]) + bv[0];
    float p1 = fmaf(aL[1], LO_INV, aH[1]) + bv[1];
    float p2 = fmaf(aL[2], LO_INV, aH[2]) + bv[2];
    float p3 = fmaf(aL[3], LO_INV, aH[3]) + bv[3];
    float A = ex2(p0), F = ex2(p1), B = ex2(p2), C = ex2(p3);
    float ig = (1.f - B) * rcp_((1.f + A) * (1.f + B));
    c = fmaf(rcp_(1.f + F), c, ig);
    float D = ex2(fminf(c * NEG_2L, 100.f));
    return (1.f - D) * rcp_((1.f + C) * (1.f + D));
  };

  // Interval t: G0 = L1(t) gates; G1 = L2(t-1) gates. One barrier/interval.
  auto iter = [&](int t, int par, bool doL2) {
    const int h1sF = par * 128, h2sF = 256 + par * 128;
    const int h1s8 = par * 64, h2s8 = 128 + par * 64;
    // x(t+1) issue at TOP: ~full interval before the barrier drain
    int tn = (t + 1 < SEQL) ? t + 1 : SEQL - 1;
    xa = *(const f32x4*)(xp + tn * 32);
    xb = *(const f32x4*)(xp + tn * 32 + 4);

    f32x4 aH[4], aL[4];
    // ---- L1: G0 = W0 @ [x(t)|h1(t-1)] ----
#pragma unroll
    for (int m = 0; m < 4; ++m) aH[m] = mfma16(w0h[m][0], ax, z4);
#pragma unroll
    for (int m = 0; m < 4; ++m) aL[m] = mfma8(lo0(0, m), ax8, z4);
#pragma unroll
    for (int ks = 0; ks < 2; ++ks) {
#pragma unroll
      for (int m = 0; m < 4; ++m)
        aH[m] = mfma16(w0h[m][ks + 1], ah1f[ks], aH[m]);
#pragma unroll
      for (int m = 0; m < 4; ++m)
        aL[m] = mfma8(lo0(ks + 1, m), fh1[ks], aL[m]);
    }
#pragma unroll
    for (int m = 0; m < 4; ++m) {
      const int cell = 4 * wave + 16 * m + q;
      f32x4 bv = *(const f32x4*)(lds + L_BIAS + cell * 16);
      float h = cellfn(aH[m], aL[m], bv, c1[m]);
      if (act) {
        *(_Float16*)(lds + L_FEX + mcol * FEXSTR + h1sF + cell * 2) =
            (_Float16)h;
        (lds + L_8EX + mcol * EX8STR + h1s8)[cell] = fp8byte(h);
      }
    }
    // ---- L2: G1 = W1 @ [h1(t-1)|h2(t-2)] ----
#pragma unroll
    for (int m = 0; m < 4; ++m) aH[m] = mfma16(w1h[m][0], ah1f[0], z4);
#pragma unroll
    for (int m = 0; m < 4; ++m) aL[m] = mfma8(lo1(0, m), fh1[0], z4);
#pragma unroll
    for (int m = 0; m < 4; ++m) aH[m] = mfma16(w1h[m][1], ah1f[1], aH[m]);
#pragma unroll
    for (int m = 0; m < 4; ++m) aL[m] = mfma8(lo1(1, m), fh1[1], aL[m]);
#pragma unroll
    for (int ks = 0; ks < 2; ++ks) {
#pragma unroll
      for (int m = 0; m < 4; ++m)
        aH[m] = mfma16(w1h[m][ks + 2], ah2f[ks], aH[m]);
#pragma unroll
      for (int m = 0; m < 4; ++m)
        aL[m] = mfma8(lo1(ks + 2, m), fh2[ks], aL[m]);
    }
    if (doL2) {
#pragma unroll
      for (int m = 0; m < 4; ++m) {
        const int cell = 4 * wave + 16 * m + q;
        f32x4 bv = *(const f32x4*)(lds + L_BIAS + 1024 + cell * 16);
        float h = cellfn(aH[m], aL[m], bv, c2[m]);
        if (act) {
          *(_Float16*)(lds + L_FEX + mcol * FEXSTR + h2sF + cell * 2) =
              (_Float16)h;
          (lds + L_8EX + mcol * EX8STR + h2s8)[cell] = fp8byte(h);
        }
      }
    }
    __syncthreads();  // the ONLY barrier per interval
    // reads for t+1 (WAR vs next interval's writes separated by next barrier)
    ah1f[0] = *(const f16x8*)(lds + L_FEX + rdF + h1sF);
    ah1f[1] = *(const f16x8*)(lds + L_FEX + rdF + h1sF + 64);
    ah2f[0] = *(const f16x8*)(lds + L_FEX + rdF + h2sF);
    ah2f[1] = *(const f16x8*)(lds + L_FEX + rdF + h2sF + 64);
    fh1[0] = *(const long*)(lds + L_8EX + rd8 + h1s8);
    fh1[1] = *(const long*)(lds + L_8EX + rd8 + h1s8 + 32);
    fh2[0] = *(const long*)(lds + L_8EX + rd8 + h2s8);
    fh2[1] = *(const long*)(lds + L_8EX + rd8 + h2s8 + 32);
    ax = cvt8(xa, xb);  // x(t+1): loaded since top of this interval
    ax8 = packfp8(xa, xb);
  };

  iter(0, 0, false);  // L1(0) only; h2 slots stay zero => h2(-1)=0
#pragma unroll 1
  for (int tp = 0; tp < 127; ++tp) {
    iter(2 * tp + 1, 1, true);
    iter(2 * tp + 2, 0, true);
  }
  iter(255, 1, true);  // L1(255) + L2(254); bottom reads h1(255), h2(254)

  // ---- Epilogue: L2(255) -> head LDS ----
  {
    f32x4 aH[4], aL[4];
#pragma unroll
    for (int m = 0; m < 4; ++m) aH[m] = mfma16(w1h[m][0], ah1f[0], z4);
#pragma unroll
    for (int m = 0; m < 4; ++m) aL[m] = mfma8(lo1(0, m), fh1[0], z4);
#pragma unroll
    for (int m = 0; m < 4; ++m) aH[m] = mfma16(w1h[m][1], ah1f[1], aH[m]);
#pragma unroll
    for (int m = 0; m < 4; ++m) aL[m] = mfma8(lo1(1, m), fh1[1], aL[m]);
#pragma unroll
    for (int ks = 0; ks < 2; ++ks) {
#pragma unroll
      for (int m = 0; m < 4; ++m)
        aH[m] = mfma16(w1h[m][ks + 2], ah2f[ks], aH[m]);
#pragma unroll
      for (int m = 0; m < 4; ++m)
        aL[m] = mfma8(lo1(ks + 2, m), fh2[ks], aL[m]);
    }
#pragma unroll
    for (int m = 0; m < 4; ++m) {
      const int cell = 4 * wave + 16 * m + q;
      f32x4 bv = *(const f32x4*)(lds + L_BIAS + 1024 + cell * 16);
      float h = cellfn(aH[m], aL[m], bv, c2[m]);
      if (act) *(float*)(lds + L_HD + mcol * HDSTR + cell * 4) = h;
    }
  }
  __syncthreads();

  // ---- Head: f = relu(h2 @ W1.T + b1); out = f @ W2.T + b2 ----
  if (tid < 128) {  // 8 outputs per block
    const int s = tid & 15, bo = tid >> 4;
    const float* h2row = (const float*)(lds + L_HD + bo * HDSTR);
    float partial = 0.f;
#pragma unroll
    for (int kk4 = 0; kk4 < 4; ++kk4) {
      int kk = s * 4 + kk4;
      float f = b1[kk];
#pragma unroll
      for (int j = 0; j < 64; j += 4) {
        f32x4 w = *(const f32x4*)(W1 + kk * 64 + j);
        f = fmaf(w[0], h2row[j], f);
        f = fmaf(w[1], h2row[j + 1], f);
        f = fmaf(w[2], h2row[j + 2], f);
        f = fmaf(w[3], h2row[j + 3], f);
      }
      f = fmaxf(f, 0.f);
      partial = fmaf(f, W2[kk], partial);
    }
    partial += __shfl_xor(partial, 8, 64);
    partial += __shfl_xor(partial, 4, 64);
    partial += __shfl_xor(partial, 2, 64);
    partial += __shfl_xor(partial, 1, 64);
    if (s == 0) out[blockIdx.x * 8 + bo] = partial + b2[0];
  }
}

extern "C" void kernel_launch(void* const* d_in, const int* in_sizes, int n_in,
                              void* d_out, int out_size, void* d_ws, size_t ws_size,
                              hipStream_t stream) {
  const float* x    = (const float*)d_in[0];
  const float* Wih0 = (const float*)d_in[1];
  const float* Whh0 = (const float*)d_in[2];
  const float* bih0 = (const float*)d_in[3];
  const float* bhh0 = (const float*)d_in[4];
  const float* Wih1 = (const float*)d_in[5];
  const float* Whh1 = (const float*)d_in[6];
  const float* bih1 = (const float*)d_in[7];
  const float* bhh1 = (const float*)d_in[8];
  const float* W1   = (const float*)d_in[9];
  const float* b1   = (const float*)d_in[10];
  const float* W2   = (const float*)d_in[11];
  const float* b2   = (const float*)d_in[12];
  unsigned char* ws = (unsigned char*)d_ws;
  float* out = (float*)d_out;

  prep<<<(57856 + 255) / 256, 256, 0, stream>>>(Wih0, Whh0, bih0, bhh0,
                                                Wih1, Whh1, bih1, bhh1, ws);
  lstm_mfma13<<<512, 256, 0, stream>>>(x, ws, W1, b1, W2, b2, out);
}

// Round 9
// 452.704 us; speedup vs baseline: 1.5779x; 1.5779x over previous
//
#include <hip/hip_runtime.h>
#include <cstdint>

typedef __attribute__((ext_vector_type(8))) _Float16 f16x8;
typedef __attribute__((ext_vector_type(4))) float f32x4;

#define SEQL 256

// ws byte offsets (prep output; identical layout to v6/v8 rounds)
#define WS_B0H   0        // [3 kstep][16 ntile][64 lane][8] f16 = 49152 B
#define WS_B0L   49152    // lo pre-scaled x2048
#define WS_B1H   98304    // [4][16][64][8] f16 hi = 65536 B, then lo contiguous
#define WS_BIAS0 229376   // 256 f32, index = cell*4+gate, pre-scaled
#define WS_BIAS1 230400

// LDS: h-exchange only (x lives in registers). Row (per batch col) = 528 B.
// h1_0@0(128B) h1_1@128 h2_0@256 h2_1@384 pad@512
#define ASTR 528
#define L_HD 8448         // head exchange: 16 rows x 272 B
#define HDSTR 272
#define LDS_TOTAL 12800

#define NEG_L   -1.4426950408889634f   // -log2(e)
#define NEG_2L  -2.8853900817779268f   // -2*log2(e)
#define LO_SCALE 2048.0f
#define LO_INV   4.8828125e-4f         // 1/2048

__device__ __forceinline__ float ex2(float x) { return __builtin_amdgcn_exp2f(x); }
__device__ __forceinline__ float rcp_(float x) { return __builtin_amdgcn_rcpf(x); }
__device__ __forceinline__ f32x4 mfma16(f16x8 a, f16x8 b, f32x4 c) {
  return __builtin_amdgcn_mfma_f32_16x16x32_f16(a, b, c, 0, 0, 0);
}
__device__ __forceinline__ f16x8 zero8() {
  f16x8 z;
#pragma unroll
  for (int i = 0; i < 8; ++i) z[i] = (_Float16)0.f;
  return z;
}
__device__ __forceinline__ f16x8 cvt8(f32x4 a, f32x4 b) {
  f16x8 r;
#pragma unroll
  for (int j = 0; j < 4; ++j) r[j] = (_Float16)a[j];
#pragma unroll
  for (int j = 0; j < 4; ++j) r[4 + j] = (_Float16)b[j];
  return r;
}

// Pack weights into MFMA fragment order (A-operand; A/B f16 fragment layouts
// identical on gfx950), f16 hi + f16 lo(x2048) split, pre-scaled by
// -log2e (i,f,o) / -2log2e (g). Identity cell order (no permutation).
__global__ __launch_bounds__(256) void prep(
    const float* __restrict__ Wih0, const float* __restrict__ Whh0,
    const float* __restrict__ bih0, const float* __restrict__ bhh0,
    const float* __restrict__ Wih1, const float* __restrict__ Whh1,
    const float* __restrict__ bih1, const float* __restrict__ bhh1,
    unsigned char* __restrict__ ws) {
  int e = blockIdx.x * 256 + threadIdx.x;
  if (e < 24576) {  // B0: K=96 = [x(32)|h1(64)]
    int j = e & 7, lane = (e >> 3) & 63, nt = (e >> 9) & 15, ks = e >> 13;
    int kdim = ks * 32 + (lane >> 4) * 8 + j;
    int col = nt * 16 + (lane & 15);   // gate-row index of the A-operand
    int ko = col >> 2, g = col & 3;
    float w = (kdim < 32) ? Wih0[(g * 64 + ko) * 32 + kdim]
                          : Whh0[(g * 64 + ko) * 64 + (kdim - 32)];
    w *= (g == 2) ? NEG_2L : NEG_L;
    _Float16 hi = (_Float16)w;
    _Float16 lo = (_Float16)((w - (float)hi) * LO_SCALE);
    ((_Float16*)(ws + WS_B0H))[e] = hi;
    ((_Float16*)(ws + WS_B0L))[e] = lo;
  } else if (e < 57344) {  // B1: K=128 = [h1(64)|h2(64)]
    int r = e - 24576;
    int j = r & 7, lane = (r >> 3) & 63, nt = (r >> 9) & 15, ks = r >> 13;
    int kdim = ks * 32 + (lane >> 4) * 8 + j;
    int col = nt * 16 + (lane & 15);
    int ko = col >> 2, g = col & 3;
    float w = (kdim < 64) ? Wih1[(g * 64 + ko) * 64 + kdim]
                          : Whh1[(g * 64 + ko) * 64 + (kdim - 64)];
    w *= (g == 2) ? NEG_2L : NEG_L;
    _Float16 hi = (_Float16)w;
    _Float16 lo = (_Float16)((w - (float)hi) * LO_SCALE);
    ((_Float16*)(ws + WS_B1H))[r] = hi;
    ((_Float16*)(ws + WS_B1H + 65536))[r] = lo;
  } else if (e < 57856) {  // biases (pre-scaled, fp32)
    int r = e - 57344;
    int col = r & 255, ko = col >> 2, g = col & 3;
    float v = (r < 256) ? bih0[g * 64 + ko] + bhh0[g * 64 + ko]
                        : bih1[g * 64 + ko] + bhh1[g * 64 + ko];
    v *= (g == 2) ? NEG_2L : NEG_L;
    ((float*)(ws + (r < 256 ? WS_BIAS0 : WS_BIAS1)))[col] = v;
  }
}

// v14 = v6/v12 structure (16 waves x 1 ntile, full N=16 tiles, single
// barrier) with ISSUE-ORDER overlap: per interval the program order is
//   G0 MFMAs(6) -> cell1 VALU -> [sched_barrier] -> G1 MFMAs(8) -> cell2
// so each wave's ~130-cycle cell1 chain issues while other waves' MFMAs
// grind the matrix pipe (in-order issue was serializing the phases when all
// 14 MFMAs were clustered first). Plain b16 h-writes (conflicts non-binding;
// shfl-packing cost LDS-pipe ops). Direct-global x, fused 8-trans cell.
__global__ __launch_bounds__(1024, 4) void lstm_mfma14(
    const float* __restrict__ x, const unsigned char* __restrict__ ws,
    const float* __restrict__ W1, const float* __restrict__ b1,
    const float* __restrict__ W2, const float* __restrict__ b2,
    float* __restrict__ out) {
  __shared__ __align__(16) unsigned char lds[LDS_TOTAL];
  const int tid = threadIdx.x;
  const int lane = tid & 63, wave = tid >> 6;  // 16 waves, 1 ntile each
  const int q = lane >> 4, mcol = lane & 15;

  // ---- Weight fragments -> registers (loop-invariant, A-operand) ----
  f16x8 b0h[3], b0l[3], b1h[4], b1l[4];
#pragma unroll
  for (int ks = 0; ks < 3; ++ks) {
    int rec = (ks * 16 + wave) * 64 + lane;
    b0h[ks] = ((const f16x8*)(ws + WS_B0H))[rec];
    b0l[ks] = ((const f16x8*)(ws + WS_B0L))[rec];
  }
#pragma unroll
  for (int ks = 0; ks < 4; ++ks) {
    int rec = (ks * 16 + wave) * 64 + lane;
    b1h[ks] = ((const f16x8*)(ws + WS_B1H))[rec];
    b1l[ks] = ((const f16x8*)(ws + WS_B1H + 65536))[rec];
  }
  // Per-lane bias: gates i,f,g,o of cell wave*4+q (enters as MFMA C-input)
  const f32x4 bias0v = ((const f32x4*)(ws + WS_BIAS0))[wave * 4 + q];
  const f32x4 bias1v = ((const f32x4*)(ws + WS_BIAS1))[wave * 4 + q];
  f32x4 z4;
  z4[0] = z4[1] = z4[2] = z4[3] = 0.f;

  // Zero h-exchange (8448 B = 2112 words): h1(-1)=h2(-1)=h2(-2)=0
  for (int i = tid; i < 2112; i += 1024) ((unsigned*)lds)[i] = 0u;

  // x: lane (q,mcol) owns batch (blockIdx*16+mcol), dims 8q..8q+7 (32 B).
  // 16 waves read the same 2KB/t working set -> L1 broadcast; VMEM pipe idle.
  const float* xp = x + (size_t)(blockIdx.x * 16 + mcol) * (SEQL * 32) + q * 8;
  f16x8 ax = cvt8(*(const f32x4*)(xp), *(const f32x4*)(xp + 4));  // x(0)
  f32x4 xa = *(const f32x4*)(xp + 32);   // x(1), full-interval in flight
  f32x4 xb = *(const f32x4*)(xp + 36);

  const int ard = mcol * ASTR + q * 16;               // fragment read base
  const int hwr = mcol * ASTR + (wave * 4 + q) * 2;   // h write base (in-slot)

  float c1 = 0.f, c2 = 0.f, h2f = 0.f;
  f16x8 ah1[2], ah2[2];
  ah1[0] = ah1[1] = ah2[0] = ah2[1] = zero8();
  __syncthreads();

  // Fused cell: 8 trans. aH carries bias via MFMA C-input.
  // gi*gg = (1-B)/((1+A)(1+B)); go*tanh(c) = (1-D)/((1+C)(1+D)).
  auto cell = [&](const f32x4& aH, const f32x4& aL, float& c) -> float {
    float p0 = fmaf(aL[0], LO_INV, aH[0]);   // i
    float p1 = fmaf(aL[1], LO_INV, aH[1]);   // f
    float p2 = fmaf(aL[2], LO_INV, aH[2]);   // g (pre-scaled -2log2e)
    float p3 = fmaf(aL[3], LO_INV, aH[3]);   // o
    float A = ex2(p0), F = ex2(p1), B = ex2(p2), C = ex2(p3);
    float ig = (1.f - B) * rcp_((1.f + A) * (1.f + B));
    c = fmaf(rcp_(1.f + F), c, ig);
    float D = ex2(fminf(c * NEG_2L, 100.f));
    return (1.f - D) * rcp_((1.f + C) * (1.f + D));
  };

  // Interval t: G0 = bias0 + W0@[x(t)|h1(t-1)]; G1 = bias1 + W1@[h1(t-1)|h2(t-2)]
  auto iter = [&](int t, int par, bool doL2) {
    const int h1s = par * 128;         // h1(t) slot
    const int h2s = 256 + par * 128;   // h2(t-1) slot

    // ---- G0: 6 MFMAs (ax register-only first covers post-barrier reads) ----
    f32x4 aH0 = mfma16(b0h[0], ax, bias0v);
    f32x4 aL0 = mfma16(b0l[0], ax, z4);
    aH0 = mfma16(b0h[1], ah1[0], aH0);
    aL0 = mfma16(b0l[1], ah1[0], aL0);
    aH0 = mfma16(b0h[2], ah1[1], aH0);
    aL0 = mfma16(b0l[2], ah1[1], aL0);
    // ---- cell 1 issues NOW: overlaps other waves' MFMA grinding ----
    float h1 = cell(aH0, aL0, c1);
    *(_Float16*)(lds + hwr + h1s) = (_Float16)h1;
    // pin the boundary: G1 MFMAs must not be hoisted above cell1
    __builtin_amdgcn_sched_barrier(0);
    // ---- G1: 8 MFMAs (inputs all read last interval; independent of cell1) ----
    f32x4 aH1 = mfma16(b1h[0], ah1[0], bias1v);
    f32x4 aL1 = mfma16(b1l[0], ah1[0], z4);
    aH1 = mfma16(b1h[1], ah1[1], aH1);
    aL1 = mfma16(b1l[1], ah1[1], aL1);
    aH1 = mfma16(b1h[2], ah2[0], aH1);
    aL1 = mfma16(b1l[2], ah2[0], aL1);
    aH1 = mfma16(b1h[3], ah2[1], aH1);
    aL1 = mfma16(b1l[3], ah2[1], aL1);
    // ---- cell 2 ----
    if (doL2) {
      float h2 = cell(aH1, aL1, c2);
      *(_Float16*)(lds + hwr + h2s) = (_Float16)h2;
    }
    // x pipeline: consume loads issued one interval ago, issue next
    ax = cvt8(xa, xb);                 // x(t+1)
    int tn = t + 2; if (tn > SEQL - 1) tn = SEQL - 1;
    xa = *(const f32x4*)(xp + tn * 32);
    xb = *(const f32x4*)(xp + tn * 32 + 4);
    __syncthreads();  // the ONLY barrier per step
    // Reads for t+1 (WAR vs next interval's writes separated by next barrier)
    ah1[0] = *(const f16x8*)(lds + ard + h1s);
    ah1[1] = *(const f16x8*)(lds + ard + h1s + 64);
    ah2[0] = *(const f16x8*)(lds + ard + h2s);
    ah2[1] = *(const f16x8*)(lds + ard + h2s + 64);
  };

  iter(0, 0, false);  // L1(0) only; h2 slot stays zero => h2(-1)=0
#pragma unroll 1
  for (int tp = 0; tp < 127; ++tp) {
    iter(2 * tp + 1, 1, true);
    iter(2 * tp + 2, 0, true);
  }
  iter(255, 1, true);  // L1(255) + L2(254); bottom reads h1(255), h2(254)

  // ---- Epilogue: L2(255) -> h2f ----
  {
    f32x4 aH = mfma16(b1h[0], ah1[0], bias1v);
    f32x4 aL = mfma16(b1l[0], ah1[0], z4);
    aH = mfma16(b1h[1], ah1[1], aH);
    aL = mfma16(b1l[1], ah1[1], aL);
#pragma unroll
    for (int ks = 0; ks < 2; ++ks) {
      aH = mfma16(b1h[ks + 2], ah2[ks], aH);
      aL = mfma16(b1l[ks + 2], ah2[ks], aL);
    }
    h2f = cell(aH, aL, c2);
  }

  // ---- Head: f = relu(h2 @ W1.T + b1); out = f @ W2.T + b2 (fp32 h2) ----
  __syncthreads();
  *(float*)(lds + L_HD + mcol * HDSTR + (wave * 4 + q) * 4) = h2f;
  __syncthreads();
  if (tid < 256) {
    const int s = tid & 15, bo = tid >> 4;
    const float* h2row = (const float*)(lds + L_HD + bo * HDSTR);
    float partial = 0.f;
#pragma unroll
    for (int kk4 = 0; kk4 < 4; ++kk4) {
      int kk = s * 4 + kk4;
      float f = b1[kk];
#pragma unroll
      for (int j = 0; j < 64; j += 4) {
        f32x4 w = *(const f32x4*)(W1 + kk * 64 + j);
        f = fmaf(w[0], h2row[j], f);
        f = fmaf(w[1], h2row[j + 1], f);
        f = fmaf(w[2], h2row[j + 2], f);
        f = fmaf(w[3], h2row[j + 3], f);
      }
      f = fmaxf(f, 0.f);
      partial = fmaf(f, W2[kk], partial);
    }
    partial += __shfl_xor(partial, 8, 64);
    partial += __shfl_xor(partial, 4, 64);
    partial += __shfl_xor(partial, 2, 64);
    partial += __shfl_xor(partial, 1, 64);
    if (s == 0) out[blockIdx.x * 16 + bo] = partial + b2[0];
  }
}

extern "C" void kernel_launch(void* const* d_in, const int* in_sizes, int n_in,
                              void* d_out, int out_size, void* d_ws, size_t ws_size,
                              hipStream_t stream) {
  const float* x    = (const float*)d_in[0];
  const float* Wih0 = (const float*)d_in[1];
  const float* Whh0 = (const float*)d_in[2];
  const float* bih0 = (const float*)d_in[3];
  const float* bhh0 = (const float*)d_in[4];
  const float* Wih1 = (const float*)d_in[5];
  const float* Whh1 = (const float*)d_in[6];
  const float* bih1 = (const float*)d_in[7];
  const float* bhh1 = (const float*)d_in[8];
  const float* W1   = (const float*)d_in[9];
  const float* b1   = (const float*)d_in[10];
  const float* W2   = (const float*)d_in[11];
  const float* b2   = (const float*)d_in[12];
  unsigned char* ws = (unsigned char*)d_ws;
  float* out = (float*)d_out;

  prep<<<(57856 + 255) / 256, 256, 0, stream>>>(Wih0, Whh0, bih0, bhh0,
                                                Wih1, Whh1, bih1, bhh1, ws);
  lstm_mfma14<<<256, 1024, 0, stream>>>(x, ws, W1, b1, W2, b2, out);
}